// Round 15
// baseline (318.782 us; speedup 1.0000x reference)
//
#include <hip/hip_runtime.h>
#include <hip/hip_bf16.h>

#define DD 512
#define HDIM 64
#define NROWS 131072

typedef __bf16 bf16x8 __attribute__((ext_vector_type(8)));
typedef float f32x4 __attribute__((ext_vector_type(4)));
typedef float f32x2 __attribute__((ext_vector_type(2)));

static __device__ __forceinline__ unsigned bfbits(float f) {
    union { float f; unsigned u; } x; x.f = f;
    unsigned r = x.u + 0x7fffu + ((x.u >> 16) & 1u);
    return r >> 16;
}
static __device__ __forceinline__ __bf16 to_bf16(float f) {
    union { unsigned short s; __bf16 b; } y; y.s = (unsigned short)bfbits(f); return y.b;
}

// Step-image element offset: p = row-or-col index, g = k-granule (8 bf16),
// e = elem. Double-XOR granule swizzle -> ds_read_b128 frag reads ~2-way.
static __device__ __forceinline__ int imgoff(int p, int g, int e) {
    return p * 64 + ((((g) ^ ((p) & 3) ^ (((p) >> 2) & 3)) & 3) << 4) + e * 2;
}

// Fragment-linear byte offset for a [512 cols][512 k] bf16 weight matrix (R7).
static __device__ __forceinline__ size_t fragoff(int c, int d) {
    return (size_t)((((c >> 6) * 64 + (d >> 5) * 4 + ((c >> 4) & 3)) << 10)
         + (((((d >> 3) & 3) << 4) + (c & 15)) << 4) + ((d & 7) << 1));
}

static __device__ __forceinline__ void gll16(const void* gsrc, void* ldst) {
    __builtin_amdgcn_global_load_lds(
        (const __attribute__((address_space(1))) unsigned int*)gsrc,
        (__attribute__((address_space(3))) unsigned int*)ldst, 16, 0, 0);
}

#define VMCNT(n) asm volatile("s_waitcnt vmcnt(" #n ")" ::: "memory")
#define LGKM0 asm volatile("s_waitcnt lgkmcnt(0)" ::: "memory")
#define MEMPIN asm volatile("" ::: "memory")   // pin VMEM issue order

// bijective XCD-chunk swizzle (m204)
static __device__ __forceinline__ int xcd_swz(int bid, int nwg) {
    const int q = nwg >> 3, r = nwg & 7;
    const int xcd = bid & 7, idx = bid >> 3;
    return (xcd < r ? xcd * (q + 1) : r * (q + 1) + (xcd - r) * q) + idx;
}

// ---------------- prep 1: k/v projections of memory (tiny) ----------------
__global__ void prep_kv(const float* __restrict__ memory,
                        const float* __restrict__ Wk, const float* __restrict__ bk,
                        const float* __restrict__ Wv, const float* __restrict__ bv,
                        float* __restrict__ kproj, float* __restrict__ vproj) {
    __shared__ float mrow[DD];
    const int m = blockIdx.x;
    const int t = threadIdx.x;
    for (int i = t; i < DD; i += 256) mrow[i] = memory[(size_t)m * DD + i];
    __syncthreads();
    for (int jj = 0; jj < 2; ++jj) {
        const int j = t + jj * 256;
        const float* wkr = Wk + (size_t)j * DD;
        const float* wvr = Wv + (size_t)j * DD;
        float sk = 0.f, sv = 0.f;
        for (int d = 0; d < DD; ++d) {
            const float md = mrow[d];
            sk += md * wkr[d];
            sv += md * wvr[d];
        }
        kproj[(size_t)m * DD + j] = sk + bk[j];
        vproj[(size_t)m * DD + j] = sv + bv[j];
    }
}

// ---------------- prep 2: fold into W2img (step images) / b2 / W3fr ----------
__global__ void prep_w(const float* __restrict__ Wq, const float* __restrict__ bq,
                       const float* __restrict__ Wo,
                       const float* __restrict__ kproj, const float* __restrict__ vproj,
                       char* __restrict__ W2img, float* __restrict__ b2,
                       char* __restrict__ W3fr) {
    const int i = blockIdx.x;   // c (score-col) for W2img/b2; j (out-col) for W3fr
    const int t = threadIdx.x;
    __shared__ float kp[HDIM];
    __shared__ float worow[DD];
    const int m = i & 63, h = i >> 6;
    if (t < HDIM) kp[t] = kproj[(size_t)m * DD + h * HDIM + t];
    for (int d = t; d < DD; d += 256) worow[d] = Wo[(size_t)i * DD + d];
    __syncthreads();
    for (int dd2 = 0; dd2 < 2; ++dd2) {
        const int d = t + dd2 * 256;
        float s = 0.f;
        #pragma unroll 8
        for (int hd = 0; hd < HDIM; ++hd)
            s += Wq[(size_t)(h * HDIM + hd) * DD + d] * kp[hd];
        *(__bf16*)(W2img + (size_t)(d >> 5) * 32768 + imgoff(i, (d >> 3) & 3, d & 7)) = to_bf16(s);
    }
    if (t == 0) {
        float s = 0.f;
        for (int hd = 0; hd < HDIM; ++hd) s += bq[h * HDIM + hd] * kp[hd];
        b2[i] = s;
    }
    for (int cc = 0; cc < 2; ++cc) {
        const int c = t + cc * 256;
        const int mc = c & 63, hc = c >> 6;
        float s = 0.f;
        #pragma unroll 8
        for (int hd = 0; hd < HDIM; ++hd)
            s += vproj[(size_t)mc * DD + hc * HDIM + hd] * worow[hc * HDIM + hd];
        *(__bf16*)(W3fr + fragoff(i, c)) = to_bf16(s);
    }
}

// ---------------- fused kernel: x@W2 + b2 -> softmax -> @W3 + bo -> out -------
// Block: 64 rows x 512 cols, 1024 threads = 16 waves (2 wr x 8 wc);
// wave = 32 rows x 64 cols = ONE head (softmax wave-local). acc[2][4] = 32 AGPR
// -> ~90 regs/wave -> 4 waves/SIMD (16 waves/CU), 2x the R14 occupancy.
// LDS 72KB: A-x images dbuf 2x4KB @0; B-W2 step images dbuf 2x32KB @8192.
// Phase 2 reuses the 64KB B region for 16 attn step-images (4KB each).
// Phase 3: A from attn images, W3 frag-linear reg-streamed (dbuf).
__global__ __launch_bounds__(1024, 4) void attn_fused(
    const float* __restrict__ x, const int* __restrict__ mask,
    const char* __restrict__ W2img, const float* __restrict__ b2,
    const char* __restrict__ W3fr, const float* __restrict__ bo,
    float* __restrict__ out) {
    __shared__ char ldsb[73728];

    const int tid = threadIdx.x;
    const int lane = tid & 63;
    const int wid = tid >> 6;             // 0..15
    const int wr = wid >> 3;              // 0..1 row half
    const int wc = wid & 7;               // 0..7 = head
    const int lc = lane & 15, grp = lane >> 4;
    const int swz = xcd_swz(blockIdx.x, gridDim.x);
    const int gr0 = swz * 64;

    // ---- A (x) staging: 1024 threads, thread -> (row, 2 k-elems)
    const int arow = tid >> 4, sub = tid & 15;       // 16 threads/row, 2 floats each
    const float* asrc = x + (size_t)(gr0 + arow) * DD + sub * 2;
    const int adst = imgoff(arow, sub >> 2, (sub & 3) * 2);
    const char* bsrc = W2img + wid * 2048 + lane * 16;

    f32x2 sreg[2];
    #define ALOAD(kt, set)  { sreg[set] = *(const f32x2*)(asrc + (kt) * 32); }
    #define AWRITE(buf, set)                                                       \
        { unsigned u = bfbits(sreg[set][0]) | (bfbits(sreg[set][1]) << 16);        \
          *(unsigned*)(ldsb + (buf) * 4096 + adst) = u; }
    #define BGLL(kt, buf)                                                          \
        { gll16(bsrc + (size_t)(kt) * 32768,                                       \
                ldsb + 8192 + (buf) * 32768 + wid * 2048);                         \
          gll16(bsrc + (size_t)(kt) * 32768 + 1024,                                \
                ldsb + 8192 + (buf) * 32768 + wid * 2048 + 1024); }
    // frag reads; XOR swizzle compile-time per m/n (wr*32, wc*64 vanish mod 4)
    #define LDA1(buf, m)                                                           \
        (*(const bf16x8*)(ldsb + (buf) * 4096 + (wr * 32 + (m) * 16 + lc) * 64     \
            + (((grp ^ (lc & 3) ^ (((m) * 4 + (lc >> 2)) & 3)) & 3) << 4)))
    #define LDB1(buf, n)                                                           \
        (*(const bf16x8*)(ldsb + 8192 + (buf) * 32768                              \
            + (wc * 64 + (n) * 16 + lc) * 64                                       \
            + (((grp ^ (lc & 3) ^ (((n) * 4 + (lc >> 2)) & 3)) & 3) << 4)))

    f32x4 acc[2][4];
    #pragma unroll
    for (int m = 0; m < 2; ++m)
        #pragma unroll
        for (int n = 0; n < 4; ++n) acc[m][n] = (f32x4){0.f, 0.f, 0.f, 0.f};

    // ---- phase 1 prologue: B(0), A(0), A(1) in flight
    BGLL(0, 0);
    MEMPIN;
    ALOAD(0, 0);
    MEMPIN;
    ALOAD(1, 1);
    VMCNT(1);          // retire B0(2)+A0(1); leave A1
    AWRITE(0, 0);
    LGKM0;
    __builtin_amdgcn_s_barrier();
    __builtin_amdgcn_sched_barrier(0);

    // ---- phase 1 K-loop: S = x @ W2
    #pragma unroll
    for (int s = 0; s < 16; ++s) {
        const int p = s & 1;
        if (s < 15) BGLL(s + 1, p ^ 1);
        MEMPIN;
        if (s < 14) ALOAD(s + 2, s & 1);
        bf16x8 af[2], bf[4];
        #pragma unroll
        for (int m = 0; m < 2; ++m) af[m] = LDA1(p, m);
        #pragma unroll
        for (int n = 0; n < 4; ++n) bf[n] = LDB1(p, n);
        __builtin_amdgcn_s_setprio(1);
        #pragma unroll
        for (int m = 0; m < 2; ++m)
            #pragma unroll
            for (int n = 0; n < 4; ++n)
                acc[m][n] = __builtin_amdgcn_mfma_f32_16x16x32_bf16(af[m], bf[n], acc[m][n], 0, 0, 0);
        __builtin_amdgcn_s_setprio(0);
        if (s < 14) {
            VMCNT(1);                        // retire B(s+1)+A(s+1); leave A(s+2)
            AWRITE(p ^ 1, (s + 1) & 1);
            LGKM0;
            __builtin_amdgcn_s_barrier();
            __builtin_amdgcn_sched_barrier(0);
        } else if (s < 15) {
            VMCNT(0);
            AWRITE(p ^ 1, 1);
            LGKM0;
            __builtin_amdgcn_s_barrier();
            __builtin_amdgcn_sched_barrier(0);
        }
    }
    __syncthreads();   // all B reads done -> B region reusable for attn images
    #undef ALOAD
    #undef AWRITE
    #undef BGLL
    #undef LDA1
    #undef LDB1

    // ---- hoist phase-3 B(0) fragment loads (hide L2 latency under softmax)
    const char* b3 = W3fr + wc * 65536 + lane * 16;
    #define LB3(kt, buf)                                                           \
        { _Pragma("unroll")                                                        \
          for (int n = 0; n < 4; ++n)                                              \
              bb3[buf][n] = *(const bf16x8*)(b3 + ((kt) * 4 + (n)) * 1024); }
    bf16x8 bb3[2][4];
    LB3(0, 0);

    // ---- phase 2: softmax (wave = head wc, 32 rows) -> attn step-images
    float b2v[4];
    #pragma unroll
    for (int n = 0; n < 4; ++n) b2v[n] = b2[wc * 64 + n * 16 + lc];

    #pragma unroll
    for (int m = 0; m < 2; ++m) {
        const int4 mv = *(const int4*)(mask + gr0 + wr * 32 + m * 16 + grp * 4);
        const int mk[4] = {mv.x, mv.y, mv.z, mv.w};
        #pragma unroll
        for (int j = 0; j < 4; ++j) {
            float s0 = (acc[m][0][j] + b2v[0]) * 0.125f;
            float s1 = (acc[m][1][j] + b2v[1]) * 0.125f;
            float s2 = (acc[m][2][j] + b2v[2]) * 0.125f;
            float s3 = (acc[m][3][j] + b2v[3]) * 0.125f;
            float mx = fmaxf(fmaxf(s0, s1), fmaxf(s2, s3));
            mx = fmaxf(mx, __shfl_xor(mx, 1));
            mx = fmaxf(mx, __shfl_xor(mx, 2));
            mx = fmaxf(mx, __shfl_xor(mx, 4));
            mx = fmaxf(mx, __shfl_xor(mx, 8));
            float p0 = __expf(s0 - mx);
            float p1 = __expf(s1 - mx);
            float p2 = __expf(s2 - mx);
            float p3 = __expf(s3 - mx);
            float sm = (p0 + p1) + (p2 + p3);
            sm += __shfl_xor(sm, 1);
            sm += __shfl_xor(sm, 2);
            sm += __shfl_xor(sm, 4);
            sm += __shfl_xor(sm, 8);
            float a[4];
            if (mk[j] == 0) {
                a[0] = a[1] = a[2] = a[3] = 0.015625f;   // fp32 -1e9 bias -> uniform attn
            } else {
                const float inv = 1.0f / sm;
                a[0] = p0 * inv; a[1] = p1 * inv; a[2] = p2 * inv; a[3] = p3 * inv;
            }
            const int rl = wr * 32 + m * 16 + grp * 4 + j;
            #pragma unroll
            for (int q = 0; q < 4; ++q) {
                const int si = wc * 2 + (q >> 1);                 // image index
                const int g2 = (q & 1) * 2 + (lc >> 3);           // k granule
                const int off = 8192 + si * 4096 + rl * 64
                    + (((g2 ^ (rl & 3) ^ ((rl >> 2) & 3)) & 3) << 4)
                    + ((lc & 7) << 1);
                *(short*)(ldsb + off) = (short)bfbits(a[q]);
            }
        }
    }
    __syncthreads();   // attn images complete

    // ---- phase 3: out = attn @ W3 (A from LDS images, B reg-streamed)
    #define LDA3(s, m)                                                             \
        (*(const bf16x8*)(ldsb + 8192 + (s) * 4096 + (wr * 32 + (m) * 16 + lc) * 64 \
            + (((grp ^ (lc & 3) ^ (((m) * 4 + (lc >> 2)) & 3)) & 3) << 4)))

    #pragma unroll
    for (int m = 0; m < 2; ++m)
        #pragma unroll
        for (int n = 0; n < 4; ++n) acc[m][n] = (f32x4){0.f, 0.f, 0.f, 0.f};

    #pragma unroll
    for (int s = 0; s < 16; ++s) {
        const int p = s & 1;
        if (s < 15) LB3(s + 1, p ^ 1);
        bf16x8 af[2];
        #pragma unroll
        for (int m = 0; m < 2; ++m) af[m] = LDA3(s, m);
        __builtin_amdgcn_s_setprio(1);
        #pragma unroll
        for (int m = 0; m < 2; ++m)
            #pragma unroll
            for (int n = 0; n < 4; ++n)
                acc[m][n] = __builtin_amdgcn_mfma_f32_16x16x32_bf16(af[m], bb3[p][n], acc[m][n], 0, 0, 0);
        __builtin_amdgcn_s_setprio(0);
    }
    #undef LB3
    #undef LDA3

    // ---- epilogue: + bo, non-temporal row-major stores
    float bov[4];
    #pragma unroll
    for (int n = 0; n < 4; ++n) bov[n] = bo[wc * 64 + n * 16 + lc];

    #pragma unroll
    for (int m = 0; m < 2; ++m) {
        #pragma unroll
        for (int j = 0; j < 4; ++j) {
            const int gr = gr0 + wr * 32 + m * 16 + grp * 4 + j;
            float* orow = out + (size_t)gr * DD + wc * 64 + lc;
            #pragma unroll
            for (int n = 0; n < 4; ++n)
                __builtin_nontemporal_store(acc[m][n][j] + bov[n], orow + n * 16);
        }
    }
}

extern "C" void kernel_launch(void* const* d_in, const int* in_sizes, int n_in,
                              void* d_out, int out_size, void* d_ws, size_t ws_size,
                              hipStream_t stream) {
    const float* qf     = (const float*)d_in[0];
    const int*   mask   = (const int*)d_in[1];
    const float* memory = (const float*)d_in[2];
    const float* Wq     = (const float*)d_in[3];
    const float* bq     = (const float*)d_in[4];
    const float* Wk     = (const float*)d_in[5];
    const float* bk     = (const float*)d_in[6];
    const float* Wv     = (const float*)d_in[7];
    const float* bv     = (const float*)d_in[8];
    const float* Wo     = (const float*)d_in[9];
    const float* bo     = (const float*)d_in[10];

    char* ws = (char*)d_ws;
    float* kproj = (float*)ws;                   // 128 KB
    float* vproj = (float*)(ws + 131072);        // 128 KB
    float* b2    = (float*)(ws + 262144);        // 2 KB
    char*  W2img = ws + 264192;                  // 512 KB (16 step-images)
    char*  W3fr  = ws + 788480;                  // 512 KB (fragment-linear)

    prep_kv<<<64, 256, 0, stream>>>(memory, Wk, bk, Wv, bv, kproj, vproj);
    prep_w<<<512, 256, 0, stream>>>(Wq, bq, Wo, kproj, vproj, W2img, b2, W3fr);
    attn_fused<<<NROWS / 64, 1024, 0, stream>>>(qf, mask, W2img, b2, W3fr, bo, (float*)d_out);
}

// Round 16
// 290.850 us; speedup vs baseline: 1.0960x; 1.0960x over previous
//
#include <hip/hip_runtime.h>
#include <hip/hip_bf16.h>

#define DD 512
#define HDIM 64
#define NROWS 131072

typedef __bf16 bf16x8 __attribute__((ext_vector_type(8)));
typedef float f32x4 __attribute__((ext_vector_type(4)));

static __device__ __forceinline__ unsigned bfbits(float f) {
    union { float f; unsigned u; } x; x.f = f;
    unsigned r = x.u + 0x7fffu + ((x.u >> 16) & 1u);
    return r >> 16;
}
static __device__ __forceinline__ __bf16 to_bf16(float f) {
    union { unsigned short s; __bf16 b; } y; y.s = (unsigned short)bfbits(f); return y.b;
}

// Step-image element offset: p = row-or-col index, g = k-granule (8 bf16),
// e = elem. Double-XOR granule swizzle -> ds_read_b128 frag reads ~2-way.
static __device__ __forceinline__ int imgoff(int p, int g, int e) {
    return p * 64 + ((((g) ^ ((p) & 3) ^ (((p) >> 2) & 3)) & 3) << 4) + e * 2;
}

// Fragment-linear byte offset for a [512 cols][512 k] bf16 weight matrix (R7):
// addr = ((c>>6)*64 + (d>>5)*4 + ((c>>4)&3))*1024 + slot*16 + (d&7)*2,
// slot = ((d>>3)&3)*16 + (c&15).  A wave frag load = base + lane*16 (coalesced).
static __device__ __forceinline__ size_t fragoff(int c, int d) {
    return (size_t)((((c >> 6) * 64 + (d >> 5) * 4 + ((c >> 4) & 3)) << 10)
         + (((((d >> 3) & 3) << 4) + (c & 15)) << 4) + ((d & 7) << 1));
}

static __device__ __forceinline__ void gll16(const void* gsrc, void* ldst) {
    __builtin_amdgcn_global_load_lds(
        (const __attribute__((address_space(1))) unsigned int*)gsrc,
        (__attribute__((address_space(3))) unsigned int*)ldst, 16, 0, 0);
}

#define VMCNT(n) asm volatile("s_waitcnt vmcnt(" #n ")" ::: "memory")
#define LGKM0 asm volatile("s_waitcnt lgkmcnt(0)" ::: "memory")
#define MEMPIN asm volatile("" ::: "memory")   // pin VMEM issue order

// bijective XCD-chunk swizzle (m204); 2048 % 8 == 0 -> simple form is exact
static __device__ __forceinline__ int xcd_swz(int bid, int nwg) {
    const int q = nwg >> 3, r = nwg & 7;
    const int xcd = bid & 7, idx = bid >> 3;
    return (xcd < r ? xcd * (q + 1) : r * (q + 1) + (xcd - r) * q) + idx;
}

// ---------------- prep 1: k/v projections of memory (tiny) ----------------
__global__ void prep_kv(const float* __restrict__ memory,
                        const float* __restrict__ Wk, const float* __restrict__ bk,
                        const float* __restrict__ Wv, const float* __restrict__ bv,
                        float* __restrict__ kproj, float* __restrict__ vproj) {
    __shared__ float mrow[DD];
    const int m = blockIdx.x;
    const int t = threadIdx.x;
    for (int i = t; i < DD; i += 256) mrow[i] = memory[(size_t)m * DD + i];
    __syncthreads();
    for (int jj = 0; jj < 2; ++jj) {
        const int j = t + jj * 256;
        const float* wkr = Wk + (size_t)j * DD;
        const float* wvr = Wv + (size_t)j * DD;
        float sk = 0.f, sv = 0.f;
        for (int d = 0; d < DD; ++d) {
            const float md = mrow[d];
            sk += md * wkr[d];
            sv += md * wvr[d];
        }
        kproj[(size_t)m * DD + j] = sk + bk[j];
        vproj[(size_t)m * DD + j] = sv + bv[j];
    }
}

// ---------------- prep 2: fold into W2img (step images) / b2 / W3fr ----------
// W2img: 16 steps x 32KB; step s holds all 512 score-cols c, k-dims d=32s..+31.
// W3fr : fragment-linear [out-col j][k-dim c].
__global__ void prep_w(const float* __restrict__ Wq, const float* __restrict__ bq,
                       const float* __restrict__ Wo,
                       const float* __restrict__ kproj, const float* __restrict__ vproj,
                       char* __restrict__ W2img, float* __restrict__ b2,
                       char* __restrict__ W3fr) {
    const int i = blockIdx.x;   // c (score-col) for W2img/b2; j (out-col) for W3fr
    const int t = threadIdx.x;
    __shared__ float kp[HDIM];
    __shared__ float worow[DD];
    const int m = i & 63, h = i >> 6;
    if (t < HDIM) kp[t] = kproj[(size_t)m * DD + h * HDIM + t];
    for (int d = t; d < DD; d += 256) worow[d] = Wo[(size_t)i * DD + d];
    __syncthreads();
    for (int dd2 = 0; dd2 < 2; ++dd2) {
        const int d = t + dd2 * 256;
        float s = 0.f;
        #pragma unroll 8
        for (int hd = 0; hd < HDIM; ++hd)
            s += Wq[(size_t)(h * HDIM + hd) * DD + d] * kp[hd];
        *(__bf16*)(W2img + (size_t)(d >> 5) * 32768 + imgoff(i, (d >> 3) & 3, d & 7)) = to_bf16(s);
    }
    if (t == 0) {
        float s = 0.f;
        for (int hd = 0; hd < HDIM; ++hd) s += bq[h * HDIM + hd] * kp[hd];
        b2[i] = s;
    }
    for (int cc = 0; cc < 2; ++cc) {
        const int c = t + cc * 256;
        const int mc = c & 63, hc = c >> 6;
        float s = 0.f;
        #pragma unroll 8
        for (int hd = 0; hd < HDIM; ++hd)
            s += vproj[(size_t)mc * DD + hc * HDIM + hd] * worow[hc * HDIM + hd];
        *(__bf16*)(W3fr + fragoff(i, c)) = to_bf16(s);
    }
}

// ---------------- fused kernel: x@W2 + b2 -> softmax -> @W3 + bo -> out -------
// Block: 64 rows x 512 cols, 4 waves; wave wn = 64 rows x cols [wn*128, +128)
// = heads 2wn, 2wn+1 (softmax wave-local). acc[4][8] = 128 AGPR.
// LDS 72KB: A-x images dbuf 2x4KB @0; B-W2 images dbuf 2x32KB @8192.
// Phase 2 reuses the 64KB B region for 16 attn step-images (4KB each).
// Phase 3 streams W3 frag-linear from L2 into registers (no LDS, no barriers).
// x loads are NON-TEMPORAL so the 268MB x stream doesn't evict the 1MB of
// weights from each XCD's L2 (weights must stay L2-resident).
__global__ __launch_bounds__(256, 2) void attn_fused(
    const float* __restrict__ x, const int* __restrict__ mask,
    const char* __restrict__ W2img, const float* __restrict__ b2,
    const char* __restrict__ W3fr, const float* __restrict__ bo,
    float* __restrict__ out) {
    __shared__ char ldsb[73728];

    const int tid = threadIdx.x;
    const int lane = tid & 63;
    const int wn = tid >> 6;              // 0..3: col quarter (2 heads)
    const int lc = lane & 15, grp = lane >> 4;
    const int swz = xcd_swz(blockIdx.x, gridDim.x);
    const int gr0 = swz * 64;

    // ---- A (x) staging: thread -> (row, granule); 32B fp32 load, 16B bf16 write
    const int arow = tid >> 2, ag = tid & 3;
    const float* asrc = x + (size_t)(gr0 + arow) * DD + ag * 8;
    const int adst = imgoff(arow, ag, 0);
    const char* bsrc = W2img + wn * 8192 + lane * 16;

    f32x4 sreg[2][2];
    #define ALOAD(kt, set)                                                         \
        { sreg[set][0] = __builtin_nontemporal_load((const f32x4*)(asrc + (kt) * 32));     \
          sreg[set][1] = __builtin_nontemporal_load((const f32x4*)(asrc + (kt) * 32 + 4)); }
    #define AWRITE(buf, set)                                                       \
        { uint4 u;                                                                 \
          u.x = bfbits(sreg[set][0][0]) | (bfbits(sreg[set][0][1]) << 16);         \
          u.y = bfbits(sreg[set][0][2]) | (bfbits(sreg[set][0][3]) << 16);         \
          u.z = bfbits(sreg[set][1][0]) | (bfbits(sreg[set][1][1]) << 16);         \
          u.w = bfbits(sreg[set][1][2]) | (bfbits(sreg[set][1][3]) << 16);         \
          *(uint4*)(ldsb + (buf) * 4096 + adst) = u; }
    #define BGLL(kt, buf)                                                          \
        { _Pragma("unroll")                                                        \
          for (int g = 0; g < 8; ++g)                                              \
              gll16(bsrc + (size_t)(kt) * 32768 + g * 1024,                        \
                    ldsb + 8192 + (buf) * 32768 + wn * 8192 + g * 1024); }
    // frag reads (swizzle XOR is per-lane compile-time per m/n)
    #define LDA1(buf, m)                                                           \
        (*(const bf16x8*)(ldsb + (buf) * 4096 + ((m) * 16 + lc) * 64               \
            + (((grp ^ (lc & 3) ^ (((m) * 4 + (lc >> 2)) & 3)) & 3) << 4)))
    #define LDB1(buf, n)                                                           \
        (*(const bf16x8*)(ldsb + 8192 + (buf) * 32768                              \
            + (wn * 128 + (n) * 16 + lc) * 64                                      \
            + (((grp ^ (lc & 3) ^ (((n) * 4 + (lc >> 2)) & 3)) & 3) << 4)))

    f32x4 acc[4][8];
    #pragma unroll
    for (int m = 0; m < 4; ++m)
        #pragma unroll
        for (int n = 0; n < 8; ++n) acc[m][n] = (f32x4){0.f, 0.f, 0.f, 0.f};

    // ---- phase 1 prologue (MEMPIN pins VMEM issue order so counted vmcnt
    // retirement (oldest-first) matches program order)
    BGLL(0, 0);
    MEMPIN;
    ALOAD(0, 0);
    MEMPIN;
    ALOAD(1, 1);
    VMCNT(2);          // B0 + A0 done; A1 (2 loads) in flight
    AWRITE(0, 0);
    LGKM0;
    __builtin_amdgcn_s_barrier();
    __builtin_amdgcn_sched_barrier(0);

    // ---- phase 1 K-loop: S = x @ W2
    #pragma unroll
    for (int s = 0; s < 16; ++s) {
        const int p = s & 1;
        if (s < 15) BGLL(s + 1, p ^ 1);
        MEMPIN;
        if (s < 14) ALOAD(s + 2, s & 1);
        bf16x8 af[4], bf[8];
        #pragma unroll
        for (int m = 0; m < 4; ++m) af[m] = LDA1(p, m);
        #pragma unroll
        for (int n = 0; n < 8; ++n) bf[n] = LDB1(p, n);
        __builtin_amdgcn_s_setprio(1);
        #pragma unroll
        for (int m = 0; m < 4; ++m)
            #pragma unroll
            for (int n = 0; n < 8; ++n)
                acc[m][n] = __builtin_amdgcn_mfma_f32_16x16x32_bf16(af[m], bf[n], acc[m][n], 0, 0, 0);
        __builtin_amdgcn_s_setprio(0);
        if (s < 14) {
            VMCNT(2);                        // drain B(s+1) + A(s+1); leave A(s+2)
            AWRITE(p ^ 1, (s + 1) & 1);
            LGKM0;
            __builtin_amdgcn_s_barrier();
            __builtin_amdgcn_sched_barrier(0);
        } else if (s < 15) {
            VMCNT(0);
            AWRITE(p ^ 1, 1);
            LGKM0;
            __builtin_amdgcn_s_barrier();
            __builtin_amdgcn_sched_barrier(0);
        }
    }
    __syncthreads();   // all B reads done -> B region reusable for attn images
    #undef ALOAD
    #undef AWRITE
    #undef BGLL
    #undef LDA1
    #undef LDB1

    // ---- hoist phase-3 B(0) fragment loads (hide L2 latency under softmax)
    const char* b3 = W3fr + wn * 131072 + lane * 16;
    #define LB3(kt, buf)                                                           \
        { _Pragma("unroll")                                                        \
          for (int n = 0; n < 8; ++n)                                              \
              bb3[buf][n] = *(const bf16x8*)(b3 + ((n) >> 2) * 65536               \
                  + (size_t)(kt) * 4096 + ((n) & 3) * 1024); }
    bf16x8 bb3[2][8];
    LB3(0, 0);

    // ---- phase 2: softmax (wave-local heads) -> attn step-images in B region
    float b2v[8];
    #pragma unroll
    for (int n = 0; n < 8; ++n) b2v[n] = b2[wn * 128 + n * 16 + lc];

    #pragma unroll
    for (int m = 0; m < 4; ++m) {
        const int4 mv = *(const int4*)(mask + gr0 + m * 16 + grp * 4);
        const int mk[4] = {mv.x, mv.y, mv.z, mv.w};
        #pragma unroll
        for (int hl = 0; hl < 2; ++hl) {
            #pragma unroll
            for (int j = 0; j < 4; ++j) {
                float s0 = (acc[m][hl * 4 + 0][j] + b2v[hl * 4 + 0]) * 0.125f;
                float s1 = (acc[m][hl * 4 + 1][j] + b2v[hl * 4 + 1]) * 0.125f;
                float s2 = (acc[m][hl * 4 + 2][j] + b2v[hl * 4 + 2]) * 0.125f;
                float s3 = (acc[m][hl * 4 + 3][j] + b2v[hl * 4 + 3]) * 0.125f;
                float mx = fmaxf(fmaxf(s0, s1), fmaxf(s2, s3));
                mx = fmaxf(mx, __shfl_xor(mx, 1));
                mx = fmaxf(mx, __shfl_xor(mx, 2));
                mx = fmaxf(mx, __shfl_xor(mx, 4));
                mx = fmaxf(mx, __shfl_xor(mx, 8));
                float p0 = __expf(s0 - mx);
                float p1 = __expf(s1 - mx);
                float p2 = __expf(s2 - mx);
                float p3 = __expf(s3 - mx);
                float sm = (p0 + p1) + (p2 + p3);
                sm += __shfl_xor(sm, 1);
                sm += __shfl_xor(sm, 2);
                sm += __shfl_xor(sm, 4);
                sm += __shfl_xor(sm, 8);
                float a[4];
                if (mk[j] == 0) {
                    a[0] = a[1] = a[2] = a[3] = 0.015625f;   // fp32 -1e9 bias -> uniform attn
                } else {
                    const float inv = 1.0f / sm;
                    a[0] = p0 * inv; a[1] = p1 * inv; a[2] = p2 * inv; a[3] = p3 * inv;
                }
                const int rl = m * 16 + grp * 4 + j;
                #pragma unroll
                for (int q = 0; q < 4; ++q) {
                    const int n = hl * 4 + q;
                    const int si = wn * 4 + (n >> 1);                 // image index
                    const int g2 = (n & 1) * 2 + (lc >> 3);           // k granule
                    const int off = 8192 + si * 4096 + rl * 64
                        + (((g2 ^ (rl & 3) ^ ((rl >> 2) & 3)) & 3) << 4)
                        + ((lc & 7) << 1);
                    *(short*)(ldsb + off) = (short)bfbits(a[q]);
                }
            }
        }
    }
    __syncthreads();   // attn images complete

    // ---- phase 3: out = attn @ W3 (A from LDS images, B reg-streamed), no barriers
    #define LDA3(s, m)                                                             \
        (*(const bf16x8*)(ldsb + 8192 + (s) * 4096 + ((m) * 16 + lc) * 64          \
            + (((grp ^ (lc & 3) ^ (((m) * 4 + (lc >> 2)) & 3)) & 3) << 4)))

    #pragma unroll
    for (int m = 0; m < 4; ++m)
        #pragma unroll
        for (int n = 0; n < 8; ++n) acc[m][n] = (f32x4){0.f, 0.f, 0.f, 0.f};

    #pragma unroll
    for (int s = 0; s < 16; ++s) {
        const int p = s & 1;
        if (s < 15) LB3(s + 1, p ^ 1);
        bf16x8 af[4];
        #pragma unroll
        for (int m = 0; m < 4; ++m) af[m] = LDA3(s, m);
        __builtin_amdgcn_s_setprio(1);
        #pragma unroll
        for (int m = 0; m < 4; ++m)
            #pragma unroll
            for (int n = 0; n < 8; ++n)
                acc[m][n] = __builtin_amdgcn_mfma_f32_16x16x32_bf16(af[m], bb3[p][n], acc[m][n], 0, 0, 0);
        __builtin_amdgcn_s_setprio(0);
    }
    #undef LB3
    #undef LDA3

    // ---- epilogue: + bo, non-temporal row-major stores
    float bov[8];
    #pragma unroll
    for (int n = 0; n < 8; ++n) bov[n] = bo[wn * 128 + n * 16 + lc];

    #pragma unroll
    for (int m = 0; m < 4; ++m) {
        #pragma unroll
        for (int j = 0; j < 4; ++j) {
            const int gr = gr0 + m * 16 + grp * 4 + j;
            float* orow = out + (size_t)gr * DD + wn * 128 + lc;
            #pragma unroll
            for (int n = 0; n < 8; ++n)
                __builtin_nontemporal_store(acc[m][n][j] + bov[n], orow + n * 16);
        }
    }
}

extern "C" void kernel_launch(void* const* d_in, const int* in_sizes, int n_in,
                              void* d_out, int out_size, void* d_ws, size_t ws_size,
                              hipStream_t stream) {
    const float* qf     = (const float*)d_in[0];
    const int*   mask   = (const int*)d_in[1];
    const float* memory = (const float*)d_in[2];
    const float* Wq     = (const float*)d_in[3];
    const float* bq     = (const float*)d_in[4];
    const float* Wk     = (const float*)d_in[5];
    const float* bk     = (const float*)d_in[6];
    const float* Wv     = (const float*)d_in[7];
    const float* bv     = (const float*)d_in[8];
    const float* Wo     = (const float*)d_in[9];
    const float* bo     = (const float*)d_in[10];

    char* ws = (char*)d_ws;
    float* kproj = (float*)ws;                   // 128 KB
    float* vproj = (float*)(ws + 131072);        // 128 KB
    float* b2    = (float*)(ws + 262144);        // 2 KB
    char*  W2img = ws + 264192;                  // 512 KB (16 step-images)
    char*  W3fr  = ws + 788480;                  // 512 KB (fragment-linear)

    prep_kv<<<64, 256, 0, stream>>>(memory, Wk, bk, Wv, bv, kproj, vproj);
    prep_w<<<512, 256, 0, stream>>>(Wq, bq, Wo, kproj, vproj, W2img, b2, W3fr);
    attn_fused<<<NROWS / 64, 256, 0, stream>>>(qf, mask, W2img, b2, W3fr, bo, (float*)d_out);
}

// Round 17
// 288.518 us; speedup vs baseline: 1.1049x; 1.0081x over previous
//
#include <hip/hip_runtime.h>
#include <hip/hip_bf16.h>

#define DD 512
#define HDIM 64
#define NROWS 131072

typedef __bf16 bf16x8 __attribute__((ext_vector_type(8)));
typedef float f32x4 __attribute__((ext_vector_type(4)));
typedef __bf16 bf16x2 __attribute__((ext_vector_type(2)));

static __device__ __forceinline__ unsigned bfbits(float f) {
    union { float f; unsigned u; } x; x.f = f;
    unsigned r = x.u + 0x7fffu + ((x.u >> 16) & 1u);
    return r >> 16;
}
static __device__ __forceinline__ __bf16 to_bf16(float f) {
    union { unsigned short s; __bf16 b; } y; y.s = (unsigned short)bfbits(f); return y.b;
}
// packed f32->bf16 pair via native casts (compiler fuses to v_cvt_pk_bf16_f32)
static __device__ __forceinline__ unsigned pk2(float lo, float hi) {
    bf16x2 t; t[0] = (__bf16)lo; t[1] = (__bf16)hi;
    union { bf16x2 b; unsigned u; } z; z.b = t; return z.u;
}

// Step-image element offset: p = row-or-col index, g = k-granule (8 bf16),
// e = elem. Double-XOR granule swizzle -> ds_read_b128 frag reads ~2-way.
static __device__ __forceinline__ int imgoff(int p, int g, int e) {
    return p * 64 + ((((g) ^ ((p) & 3) ^ (((p) >> 2) & 3)) & 3) << 4) + e * 2;
}

// Fragment-linear byte offset for a [512 cols][512 k] bf16 weight matrix (R7):
// addr = ((c>>6)*64 + (d>>5)*4 + ((c>>4)&3))*1024 + slot*16 + (d&7)*2,
// slot = ((d>>3)&3)*16 + (c&15).  A wave frag load = base + lane*16 (coalesced).
static __device__ __forceinline__ size_t fragoff(int c, int d) {
    return (size_t)((((c >> 6) * 64 + (d >> 5) * 4 + ((c >> 4) & 3)) << 10)
         + (((((d >> 3) & 3) << 4) + (c & 15)) << 4) + ((d & 7) << 1));
}

static __device__ __forceinline__ void gll16(const void* gsrc, void* ldst) {
    __builtin_amdgcn_global_load_lds(
        (const __attribute__((address_space(1))) unsigned int*)gsrc,
        (__attribute__((address_space(3))) unsigned int*)ldst, 16, 0, 0);
}

#define VMCNT(n) asm volatile("s_waitcnt vmcnt(" #n ")" ::: "memory")
#define LGKM0 asm volatile("s_waitcnt lgkmcnt(0)" ::: "memory")
#define MEMPIN asm volatile("" ::: "memory")   // pin VMEM issue order

// bijective XCD-chunk swizzle (m204); 2048 % 8 == 0 -> simple form is exact
static __device__ __forceinline__ int xcd_swz(int bid, int nwg) {
    const int q = nwg >> 3, r = nwg & 7;
    const int xcd = bid & 7, idx = bid >> 3;
    return (xcd < r ? xcd * (q + 1) : r * (q + 1) + (xcd - r) * q) + idx;
}

// ---------------- prep 1: k/v projections of memory (tiny) ----------------
__global__ void prep_kv(const float* __restrict__ memory,
                        const float* __restrict__ Wk, const float* __restrict__ bk,
                        const float* __restrict__ Wv, const float* __restrict__ bv,
                        float* __restrict__ kproj, float* __restrict__ vproj) {
    __shared__ float mrow[DD];
    const int m = blockIdx.x;
    const int t = threadIdx.x;
    for (int i = t; i < DD; i += 256) mrow[i] = memory[(size_t)m * DD + i];
    __syncthreads();
    for (int jj = 0; jj < 2; ++jj) {
        const int j = t + jj * 256;
        const float* wkr = Wk + (size_t)j * DD;
        const float* wvr = Wv + (size_t)j * DD;
        float sk = 0.f, sv = 0.f;
        for (int d = 0; d < DD; ++d) {
            const float md = mrow[d];
            sk += md * wkr[d];
            sv += md * wvr[d];
        }
        kproj[(size_t)m * DD + j] = sk + bk[j];
        vproj[(size_t)m * DD + j] = sv + bv[j];
    }
}

// ---------------- prep 2: fold into W2img (step images) / b2 / W3fr ----------
// W2img: 16 steps x 32KB; step s holds all 512 score-cols c, k-dims d=32s..+31.
// W3fr : fragment-linear [out-col j][k-dim c], with k PI-PERMUTED within each
// 32-block: slot = ((c&15)<<1)|((c>>4)&1). The attn images (GEMM2's A) use the
// same permutation -> dot product unchanged, but the softmax writer's two
// values per image become byte-adjacent (one u32 write instead of two u16).
__global__ void prep_w(const float* __restrict__ Wq, const float* __restrict__ bq,
                       const float* __restrict__ Wo,
                       const float* __restrict__ kproj, const float* __restrict__ vproj,
                       char* __restrict__ W2img, float* __restrict__ b2,
                       char* __restrict__ W3fr) {
    const int i = blockIdx.x;   // c (score-col) for W2img/b2; j (out-col) for W3fr
    const int t = threadIdx.x;
    __shared__ float kp[HDIM];
    __shared__ float worow[DD];
    const int m = i & 63, h = i >> 6;
    if (t < HDIM) kp[t] = kproj[(size_t)m * DD + h * HDIM + t];
    for (int d = t; d < DD; d += 256) worow[d] = Wo[(size_t)i * DD + d];
    __syncthreads();
    for (int dd2 = 0; dd2 < 2; ++dd2) {
        const int d = t + dd2 * 256;
        float s = 0.f;
        #pragma unroll 8
        for (int hd = 0; hd < HDIM; ++hd)
            s += Wq[(size_t)(h * HDIM + hd) * DD + d] * kp[hd];
        *(__bf16*)(W2img + (size_t)(d >> 5) * 32768 + imgoff(i, (d >> 3) & 3, d & 7)) = to_bf16(s);
    }
    if (t == 0) {
        float s = 0.f;
        for (int hd = 0; hd < HDIM; ++hd) s += bq[h * HDIM + hd] * kp[hd];
        b2[i] = s;
    }
    for (int cc = 0; cc < 2; ++cc) {
        const int c = t + cc * 256;
        const int mc = c & 63, hc = c >> 6;
        float s = 0.f;
        #pragma unroll 8
        for (int hd = 0; hd < HDIM; ++hd)
            s += vproj[(size_t)mc * DD + hc * HDIM + hd] * worow[hc * HDIM + hd];
        const int cp = (c & ~31) | (((c & 15) << 1) | ((c >> 4) & 1));   // pi-permute k
        *(__bf16*)(W3fr + fragoff(i, cp)) = to_bf16(s);
    }
}

// ---------------- fused kernel: x@W2 + b2 -> softmax -> @W3 + bo -> out -------
// Block: 64 rows x 512 cols, 4 waves; wave wn = 64 rows x cols [wn*128, +128)
// = heads 2wn, 2wn+1 (softmax wave-local). acc[4][8] = 128 AGPR.
// LDS 72KB: A-x images dbuf 2x4KB @0; B-W2 images dbuf 2x32KB @8192.
// Phase 2 reuses the 64KB B region for 16 attn step-images (4KB each).
// Phase 3 streams W3 frag-linear from L2 into registers (no LDS, no barriers).
// x loads are NON-TEMPORAL so the 268MB x stream doesn't evict the 1MB of
// weights from each XCD's L2 (weights must stay L2-resident).
__global__ __launch_bounds__(256, 2) void attn_fused(
    const float* __restrict__ x, const int* __restrict__ mask,
    const char* __restrict__ W2img, const float* __restrict__ b2,
    const char* __restrict__ W3fr, const float* __restrict__ bo,
    float* __restrict__ out) {
    __shared__ char ldsb[73728];

    const int tid = threadIdx.x;
    const int lane = tid & 63;
    const int wn = tid >> 6;              // 0..3: col quarter (2 heads)
    const int lc = lane & 15, grp = lane >> 4;
    const int swz = xcd_swz(blockIdx.x, gridDim.x);
    const int gr0 = swz * 64;

    // ---- A (x) staging: thread -> (row, granule); 32B fp32 load, 16B bf16 write
    const int arow = tid >> 2, ag = tid & 3;
    const float* asrc = x + (size_t)(gr0 + arow) * DD + ag * 8;
    const int adst = imgoff(arow, ag, 0);
    const char* bsrc = W2img + wn * 8192 + lane * 16;

    f32x4 sreg[2][2];
    #define ALOAD(kt, set)                                                         \
        { sreg[set][0] = __builtin_nontemporal_load((const f32x4*)(asrc + (kt) * 32));     \
          sreg[set][1] = __builtin_nontemporal_load((const f32x4*)(asrc + (kt) * 32 + 4)); }
    #define AWRITE(buf, set)                                                       \
        { uint4 u;                                                                 \
          u.x = pk2(sreg[set][0][0], sreg[set][0][1]);                             \
          u.y = pk2(sreg[set][0][2], sreg[set][0][3]);                             \
          u.z = pk2(sreg[set][1][0], sreg[set][1][1]);                             \
          u.w = pk2(sreg[set][1][2], sreg[set][1][3]);                             \
          *(uint4*)(ldsb + (buf) * 4096 + adst) = u; }
    #define BGLL(kt, buf)                                                          \
        { _Pragma("unroll")                                                        \
          for (int g = 0; g < 8; ++g)                                              \
              gll16(bsrc + (size_t)(kt) * 32768 + g * 1024,                        \
                    ldsb + 8192 + (buf) * 32768 + wn * 8192 + g * 1024); }
    // frag reads (swizzle XOR is per-lane compile-time per m/n)
    #define LDA1(buf, m)                                                           \
        (*(const bf16x8*)(ldsb + (buf) * 4096 + ((m) * 16 + lc) * 64               \
            + (((grp ^ (lc & 3) ^ (((m) * 4 + (lc >> 2)) & 3)) & 3) << 4)))
    #define LDB1(buf, n)                                                           \
        (*(const bf16x8*)(ldsb + 8192 + (buf) * 32768                              \
            + (wn * 128 + (n) * 16 + lc) * 64                                      \
            + (((grp ^ (lc & 3) ^ (((n) * 4 + (lc >> 2)) & 3)) & 3) << 4)))

    f32x4 acc[4][8];
    #pragma unroll
    for (int m = 0; m < 4; ++m)
        #pragma unroll
        for (int n = 0; n < 8; ++n) acc[m][n] = (f32x4){0.f, 0.f, 0.f, 0.f};

    // ---- phase 1 prologue (MEMPIN pins VMEM issue order so counted vmcnt
    // retirement (oldest-first) matches program order)
    BGLL(0, 0);
    MEMPIN;
    ALOAD(0, 0);
    MEMPIN;
    ALOAD(1, 1);
    VMCNT(2);          // B0 + A0 done; A1 (2 loads) in flight
    AWRITE(0, 0);
    LGKM0;
    __builtin_amdgcn_s_barrier();
    __builtin_amdgcn_sched_barrier(0);

    // ---- phase 1 K-loop: S = x @ W2
    #pragma unroll
    for (int s = 0; s < 16; ++s) {
        const int p = s & 1;
        if (s < 15) BGLL(s + 1, p ^ 1);
        MEMPIN;
        if (s < 14) ALOAD(s + 2, s & 1);
        bf16x8 af[4], bf[8];
        #pragma unroll
        for (int m = 0; m < 4; ++m) af[m] = LDA1(p, m);
        #pragma unroll
        for (int n = 0; n < 8; ++n) bf[n] = LDB1(p, n);
        __builtin_amdgcn_s_setprio(1);
        #pragma unroll
        for (int m = 0; m < 4; ++m)
            #pragma unroll
            for (int n = 0; n < 8; ++n)
                acc[m][n] = __builtin_amdgcn_mfma_f32_16x16x32_bf16(af[m], bf[n], acc[m][n], 0, 0, 0);
        __builtin_amdgcn_s_setprio(0);
        if (s < 14) {
            VMCNT(2);                        // drain B(s+1) + A(s+1); leave A(s+2)
            AWRITE(p ^ 1, (s + 1) & 1);
            LGKM0;
            __builtin_amdgcn_s_barrier();
            __builtin_amdgcn_sched_barrier(0);
        } else if (s < 15) {
            VMCNT(0);
            AWRITE(p ^ 1, 1);
            LGKM0;
            __builtin_amdgcn_s_barrier();
            __builtin_amdgcn_sched_barrier(0);
        }
    }
    __syncthreads();   // all B reads done -> B region reusable for attn images
    #undef ALOAD
    #undef AWRITE
    #undef BGLL
    #undef LDA1
    #undef LDB1

    // ---- hoist phase-3 B(0) fragment loads (hide L2 latency under softmax)
    const char* b3 = W3fr + wn * 131072 + lane * 16;
    #define LB3(kt, buf)                                                           \
        { _Pragma("unroll")                                                        \
          for (int n = 0; n < 8; ++n)                                              \
              bb3[buf][n] = *(const bf16x8*)(b3 + ((n) >> 2) * 65536               \
                  + (size_t)(kt) * 4096 + ((n) & 3) * 1024); }
    bf16x8 bb3[2][8];
    LB3(0, 0);

    // ---- phase 2: softmax (wave-local heads) -> attn step-images in B region
    // pi-packed writes: thread's two values per image are slots 2lc, 2lc+1 ->
    // one u32 at row rl, granule lc>>2 (swizzled), byte (lc&3)*4.
    float b2v[8];
    #pragma unroll
    for (int n = 0; n < 8; ++n) b2v[n] = b2[wn * 128 + n * 16 + lc];

    #pragma unroll
    for (int m = 0; m < 4; ++m) {
        const int4 mv = *(const int4*)(mask + gr0 + m * 16 + grp * 4);
        const int mk[4] = {mv.x, mv.y, mv.z, mv.w};
        #pragma unroll
        for (int hl = 0; hl < 2; ++hl) {
            #pragma unroll
            for (int j = 0; j < 4; ++j) {
                float s0 = (acc[m][hl * 4 + 0][j] + b2v[hl * 4 + 0]) * 0.125f;
                float s1 = (acc[m][hl * 4 + 1][j] + b2v[hl * 4 + 1]) * 0.125f;
                float s2 = (acc[m][hl * 4 + 2][j] + b2v[hl * 4 + 2]) * 0.125f;
                float s3 = (acc[m][hl * 4 + 3][j] + b2v[hl * 4 + 3]) * 0.125f;
                float mx = fmaxf(fmaxf(s0, s1), fmaxf(s2, s3));
                mx = fmaxf(mx, __shfl_xor(mx, 1));
                mx = fmaxf(mx, __shfl_xor(mx, 2));
                mx = fmaxf(mx, __shfl_xor(mx, 4));
                mx = fmaxf(mx, __shfl_xor(mx, 8));
                float p0 = __expf(s0 - mx);
                float p1 = __expf(s1 - mx);
                float p2 = __expf(s2 - mx);
                float p3 = __expf(s3 - mx);
                float sm = (p0 + p1) + (p2 + p3);
                sm += __shfl_xor(sm, 1);
                sm += __shfl_xor(sm, 2);
                sm += __shfl_xor(sm, 4);
                sm += __shfl_xor(sm, 8);
                float a0, a1, a2, a3;
                if (mk[j] == 0) {
                    a0 = a1 = a2 = a3 = 0.015625f;   // fp32 -1e9 bias -> uniform attn
                } else {
                    const float inv = 1.0f / sm;
                    a0 = p0 * inv; a1 = p1 * inv; a2 = p2 * inv; a3 = p3 * inv;
                }
                const int rl = m * 16 + grp * 4 + j;
                const int gp = ((lc >> 2) ^ (rl & 3) ^ ((rl >> 2) & 3)) & 3;
                const int base = 8192 + rl * 64 + (gp << 4) + (lc & 3) * 4;
                const int si0 = wn * 4 + hl * 2;
                *(unsigned*)(ldsb + base + si0 * 4096)       = pk2(a0, a1);
                *(unsigned*)(ldsb + base + (si0 + 1) * 4096) = pk2(a2, a3);
            }
        }
    }
    __syncthreads();   // attn images complete

    // ---- phase 3: out = attn @ W3 (A from LDS images, B reg-streamed), no barriers
    #define LDA3(s, m)                                                             \
        (*(const bf16x8*)(ldsb + 8192 + (s) * 4096 + ((m) * 16 + lc) * 64          \
            + (((grp ^ (lc & 3) ^ (((m) * 4 + (lc >> 2)) & 3)) & 3) << 4)))

    #pragma unroll
    for (int m = 0; m < 4; ++m)
        #pragma unroll
        for (int n = 0; n < 8; ++n) acc[m][n] = (f32x4){0.f, 0.f, 0.f, 0.f};

    #pragma unroll
    for (int s = 0; s < 16; ++s) {
        const int p = s & 1;
        if (s < 15) LB3(s + 1, p ^ 1);
        bf16x8 af[4];
        #pragma unroll
        for (int m = 0; m < 4; ++m) af[m] = LDA3(s, m);
        __builtin_amdgcn_s_setprio(1);
        #pragma unroll
        for (int m = 0; m < 4; ++m)
            #pragma unroll
            for (int n = 0; n < 8; ++n)
                acc[m][n] = __builtin_amdgcn_mfma_f32_16x16x32_bf16(af[m], bb3[p][n], acc[m][n], 0, 0, 0);
        __builtin_amdgcn_s_setprio(0);
    }
    #undef LB3
    #undef LDA3

    // ---- epilogue: + bo, non-temporal row-major stores
    float bov[8];
    #pragma unroll
    for (int n = 0; n < 8; ++n) bov[n] = bo[wn * 128 + n * 16 + lc];

    #pragma unroll
    for (int m = 0; m < 4; ++m) {
        #pragma unroll
        for (int j = 0; j < 4; ++j) {
            const int gr = gr0 + m * 16 + grp * 4 + j;
            float* orow = out + (size_t)gr * DD + wn * 128 + lc;
            #pragma unroll
            for (int n = 0; n < 8; ++n)
                __builtin_nontemporal_store(acc[m][n][j] + bov[n], orow + n * 16);
        }
    }
}

extern "C" void kernel_launch(void* const* d_in, const int* in_sizes, int n_in,
                              void* d_out, int out_size, void* d_ws, size_t ws_size,
                              hipStream_t stream) {
    const float* qf     = (const float*)d_in[0];
    const int*   mask   = (const int*)d_in[1];
    const float* memory = (const float*)d_in[2];
    const float* Wq     = (const float*)d_in[3];
    const float* bq     = (const float*)d_in[4];
    const float* Wk     = (const float*)d_in[5];
    const float* bk     = (const float*)d_in[6];
    const float* Wv     = (const float*)d_in[7];
    const float* bv     = (const float*)d_in[8];
    const float* Wo     = (const float*)d_in[9];
    const float* bo     = (const float*)d_in[10];

    char* ws = (char*)d_ws;
    float* kproj = (float*)ws;                   // 128 KB
    float* vproj = (float*)(ws + 131072);        // 128 KB
    float* b2    = (float*)(ws + 262144);        // 2 KB
    char*  W2img = ws + 264192;                  // 512 KB (16 step-images)
    char*  W3fr  = ws + 788480;                  // 512 KB (fragment-linear, pi-k)

    prep_kv<<<64, 256, 0, stream>>>(memory, Wk, bk, Wv, bv, kproj, vproj);
    prep_w<<<512, 256, 0, stream>>>(Wq, bq, Wo, kproj, vproj, W2img, b2, W3fr);
    attn_fused<<<NROWS / 64, 256, 0, stream>>>(qf, mask, W2img, b2, W3fr, bo, (float*)d_out);
}

// Round 18
// 278.447 us; speedup vs baseline: 1.1449x; 1.0362x over previous
//
#include <hip/hip_runtime.h>
#include <hip/hip_bf16.h>

#define DD 512
#define HDIM 64
#define NROWS 131072

typedef __bf16 bf16x8 __attribute__((ext_vector_type(8)));
typedef float f32x4 __attribute__((ext_vector_type(4)));
typedef __bf16 bf16x2 __attribute__((ext_vector_type(2)));

static __device__ __forceinline__ unsigned bfbits(float f) {
    union { float f; unsigned u; } x; x.f = f;
    unsigned r = x.u + 0x7fffu + ((x.u >> 16) & 1u);
    return r >> 16;
}
static __device__ __forceinline__ __bf16 to_bf16(float f) {
    union { unsigned short s; __bf16 b; } y; y.s = (unsigned short)bfbits(f); return y.b;
}
// packed f32->bf16 pair via native casts (compiler fuses to v_cvt_pk_bf16_f32)
static __device__ __forceinline__ unsigned pk2(float lo, float hi) {
    bf16x2 t; t[0] = (__bf16)lo; t[1] = (__bf16)hi;
    union { bf16x2 b; unsigned u; } z; z.b = t; return z.u;
}

// Step-image element offset: p = row-or-col index, g = k-granule (8 bf16),
// e = elem. Double-XOR granule swizzle -> ds_read_b128 frag reads ~2-way.
static __device__ __forceinline__ int imgoff(int p, int g, int e) {
    return p * 64 + ((((g) ^ ((p) & 3) ^ (((p) >> 2) & 3)) & 3) << 4) + e * 2;
}

// Fragment-linear byte offset for a [512 cols][512 k] bf16 weight matrix (R7):
// addr = ((c>>6)*64 + (d>>5)*4 + ((c>>4)&3))*1024 + slot*16 + (d&7)*2,
// slot = ((d>>3)&3)*16 + (c&15).  A wave frag load = base + lane*16 (coalesced).
static __device__ __forceinline__ size_t fragoff(int c, int d) {
    return (size_t)((((c >> 6) * 64 + (d >> 5) * 4 + ((c >> 4) & 3)) << 10)
         + (((((d >> 3) & 3) << 4) + (c & 15)) << 4) + ((d & 7) << 1));
}

static __device__ __forceinline__ void gll16(const void* gsrc, void* ldst) {
    __builtin_amdgcn_global_load_lds(
        (const __attribute__((address_space(1))) unsigned int*)gsrc,
        (__attribute__((address_space(3))) unsigned int*)ldst, 16, 0, 0);
}

#define VMCNT(n) asm volatile("s_waitcnt vmcnt(" #n ")" ::: "memory")
#define LGKM0 asm volatile("s_waitcnt lgkmcnt(0)" ::: "memory")
#define MEMPIN asm volatile("" ::: "memory")   // pin VMEM issue order

// bijective XCD-chunk swizzle (m204); 2048 % 8 == 0 -> simple form is exact
static __device__ __forceinline__ int xcd_swz(int bid, int nwg) {
    const int q = nwg >> 3, r = nwg & 7;
    const int xcd = bid & 7, idx = bid >> 3;
    return (xcd < r ? xcd * (q + 1) : r * (q + 1) + (xcd - r) * q) + idx;
}

// ---------------- prep 1: k/v projections (tiled, W read once) ----------------
// 32 blocks: b>>4 selects Wk->kproj / Wv->vproj; (b&15)*32 = j-column group.
// Block computes proj[m=0..63][j0..j0+31] via 8 K-tiles of 64 staged in LDS.
__global__ __launch_bounds__(256) void prep_kv(
    const float* __restrict__ memory,
    const float* __restrict__ Wk, const float* __restrict__ bk,
    const float* __restrict__ Wv, const float* __restrict__ bv,
    float* __restrict__ kproj, float* __restrict__ vproj) {
    __shared__ float memLds[64 * 65];
    __shared__ float wLds[32 * 65];
    const int t = threadIdx.x;
    const int b = blockIdx.x;
    const int mat = b >> 4;
    const int j0 = (b & 15) * 32;
    const float* W = mat ? Wv : Wk;
    const float* bias = mat ? bv : bk;
    float* proj = mat ? vproj : kproj;

    const int jloc = t >> 3;     // 0..31
    const int mbase = t & 7;
    float acc[8] = {0.f, 0.f, 0.f, 0.f, 0.f, 0.f, 0.f, 0.f};

    for (int dt = 0; dt < 8; ++dt) {
        const int d0 = dt * 64;
        __syncthreads();
        #pragma unroll
        for (int r = 0; r < 16; ++r) {
            const int row = r * 4 + (t >> 6);
            const int dd = t & 63;
            memLds[row * 65 + dd] = memory[(size_t)row * DD + d0 + dd];
        }
        #pragma unroll
        for (int r = 0; r < 8; ++r) {
            const int row = r * 4 + (t >> 6);
            const int dd = t & 63;
            wLds[row * 65 + dd] = W[(size_t)(j0 + row) * DD + d0 + dd];
        }
        __syncthreads();
        for (int d = 0; d < 64; ++d) {
            const float wv = wLds[jloc * 65 + d];
            #pragma unroll
            for (int i = 0; i < 8; ++i)
                acc[i] += memLds[(mbase + i * 8) * 65 + d] * wv;
        }
    }
    const float bj = bias[j0 + jloc];
    #pragma unroll
    for (int i = 0; i < 8; ++i)
        proj[(size_t)(mbase + i * 8) * DD + j0 + jloc] = acc[i] + bj;
}

// ---------------- prep 2: fold into W2img / b2 / W3fr (tiled) ----------------
// 64 blocks. Role A (b<32): (h = b>>2, dq = b&3): W2img for head h, d-quarter.
// Role B (b>=32): (hc, jq): W3fr for k-head hc, out-col quarter jq.
// Writes use the same imgoff/fragoff/pi helpers the fused kernel reads.
__global__ __launch_bounds__(256) void prep_w(
    const float* __restrict__ Wq, const float* __restrict__ bq,
    const float* __restrict__ Wo,
    const float* __restrict__ kproj, const float* __restrict__ vproj,
    char* __restrict__ W2img, float* __restrict__ b2,
    char* __restrict__ W3fr) {
    __shared__ float aLds[64 * 65];
    __shared__ float bLds[64 * 65];
    const int t = threadIdx.x;
    const int b = blockIdx.x;

    if (b < 32) {
        const int h = b >> 2, dq = b & 3;
        #pragma unroll
        for (int r = 0; r < 16; ++r) {
            const int row = r * 4 + (t >> 6), col = t & 63;
            aLds[row * 65 + col] = kproj[(size_t)row * DD + h * 64 + col];   // kp[m][hd]
        }
        __syncthreads();
        if (dq == 0 && t < 64) {
            float s = 0.f;
            for (int hd = 0; hd < 64; ++hd) s += bq[h * 64 + hd] * aLds[t * 65 + hd];
            b2[h * 64 + t] = s;
        }
        for (int dt = 0; dt < 2; ++dt) {
            const int d0 = dq * 128 + dt * 64;
            __syncthreads();
            #pragma unroll
            for (int r = 0; r < 16; ++r) {
                const int row = r * 4 + (t >> 6), col = t & 63;
                bLds[row * 65 + col] = Wq[(size_t)(h * 64 + row) * DD + d0 + col]; // wq[hd][d]
            }
            __syncthreads();
            #pragma unroll
            for (int uu = 0; uu < 2; ++uu) {
                const int u = t + 256 * uu;
                const int m = u & 63, oct = u >> 6;   // oct 0..7
                float acc[8] = {0.f, 0.f, 0.f, 0.f, 0.f, 0.f, 0.f, 0.f};
                for (int hd = 0; hd < 64; ++hd) {
                    const float kv = aLds[m * 65 + hd];
                    #pragma unroll
                    for (int e = 0; e < 8; ++e)
                        acc[e] += kv * bLds[hd * 65 + oct * 8 + e];
                }
                const int d = d0 + oct * 8;
                bf16x8 v;
                #pragma unroll
                for (int e = 0; e < 8; ++e) v[e] = to_bf16(acc[e]);
                *(bf16x8*)(W2img + (size_t)(d >> 5) * 32768
                           + imgoff(h * 64 + m, (d >> 3) & 3, 0)) = v;
            }
        }
    } else {
        const int hc = (b - 32) >> 2, jq = (b - 32) & 3;
        #pragma unroll
        for (int r = 0; r < 16; ++r) {
            const int row = r * 4 + (t >> 6), col = t & 63;
            aLds[row * 65 + col] = vproj[(size_t)row * DD + hc * 64 + col];  // vp[mc][hd]
        }
        for (int jt = 0; jt < 2; ++jt) {
            const int j0 = jq * 128 + jt * 64;
            __syncthreads();
            #pragma unroll
            for (int r = 0; r < 16; ++r) {
                const int row = r * 4 + (t >> 6), col = t & 63;
                bLds[row * 65 + col] = Wo[(size_t)(j0 + row) * DD + hc * 64 + col]; // wo[jl][hd]
            }
            __syncthreads();
            #pragma unroll
            for (int uu = 0; uu < 2; ++uu) {
                const int u = t + 256 * uu;
                const int jl = u & 63, w = u >> 6;       // w 0..7
                const int blk = w >> 2, oct = w & 3;
                float acc[8] = {0.f, 0.f, 0.f, 0.f, 0.f, 0.f, 0.f, 0.f};
                for (int hd = 0; hd < 64; ++hd) {
                    const float wv = bLds[jl * 65 + hd];
                    #pragma unroll
                    for (int e = 0; e < 8; ++e) {
                        const int s = oct * 8 + e;
                        const int cl = (s >> 1) + ((s & 1) << 4);   // inverse pi
                        acc[e] += wv * aLds[(blk * 32 + cl) * 65 + hd];
                    }
                }
                const int cp0 = hc * 64 + blk * 32 + oct * 8;       // permuted k index
                bf16x8 v;
                #pragma unroll
                for (int e = 0; e < 8; ++e) v[e] = to_bf16(acc[e]);
                *(bf16x8*)(W3fr + fragoff(j0 + jl, cp0)) = v;
            }
        }
    }
}

// ---------------- fused kernel: x@W2 + b2 -> softmax -> @W3 + bo -> out -------
// (unchanged from R17 — passed at 226 us, absmax 0.0078)
__global__ __launch_bounds__(256, 2) void attn_fused(
    const float* __restrict__ x, const int* __restrict__ mask,
    const char* __restrict__ W2img, const float* __restrict__ b2,
    const char* __restrict__ W3fr, const float* __restrict__ bo,
    float* __restrict__ out) {
    __shared__ char ldsb[73728];

    const int tid = threadIdx.x;
    const int lane = tid & 63;
    const int wn = tid >> 6;              // 0..3: col quarter (2 heads)
    const int lc = lane & 15, grp = lane >> 4;
    const int swz = xcd_swz(blockIdx.x, gridDim.x);
    const int gr0 = swz * 64;

    // ---- A (x) staging: thread -> (row, granule); 32B fp32 load, 16B bf16 write
    const int arow = tid >> 2, ag = tid & 3;
    const float* asrc = x + (size_t)(gr0 + arow) * DD + ag * 8;
    const int adst = imgoff(arow, ag, 0);
    const char* bsrc = W2img + wn * 8192 + lane * 16;

    f32x4 sreg[2][2];
    #define ALOAD(kt, set)                                                         \
        { sreg[set][0] = __builtin_nontemporal_load((const f32x4*)(asrc + (kt) * 32));     \
          sreg[set][1] = __builtin_nontemporal_load((const f32x4*)(asrc + (kt) * 32 + 4)); }
    #define AWRITE(buf, set)                                                       \
        { uint4 u;                                                                 \
          u.x = pk2(sreg[set][0][0], sreg[set][0][1]);                             \
          u.y = pk2(sreg[set][0][2], sreg[set][0][3]);                             \
          u.z = pk2(sreg[set][1][0], sreg[set][1][1]);                             \
          u.w = pk2(sreg[set][1][2], sreg[set][1][3]);                             \
          *(uint4*)(ldsb + (buf) * 4096 + adst) = u; }
    #define BGLL(kt, buf)                                                          \
        { _Pragma("unroll")                                                        \
          for (int g = 0; g < 8; ++g)                                              \
              gll16(bsrc + (size_t)(kt) * 32768 + g * 1024,                        \
                    ldsb + 8192 + (buf) * 32768 + wn * 8192 + g * 1024); }
    // frag reads (swizzle XOR is per-lane compile-time per m/n)
    #define LDA1(buf, m)                                                           \
        (*(const bf16x8*)(ldsb + (buf) * 4096 + ((m) * 16 + lc) * 64               \
            + (((grp ^ (lc & 3) ^ (((m) * 4 + (lc >> 2)) & 3)) & 3) << 4)))
    #define LDB1(buf, n)                                                           \
        (*(const bf16x8*)(ldsb + 8192 + (buf) * 32768                              \
            + (wn * 128 + (n) * 16 + lc) * 64                                      \
            + (((grp ^ (lc & 3) ^ (((n) * 4 + (lc >> 2)) & 3)) & 3) << 4)))

    f32x4 acc[4][8];
    #pragma unroll
    for (int m = 0; m < 4; ++m)
        #pragma unroll
        for (int n = 0; n < 8; ++n) acc[m][n] = (f32x4){0.f, 0.f, 0.f, 0.f};

    // ---- phase 1 prologue (MEMPIN pins VMEM issue order so counted vmcnt
    // retirement (oldest-first) matches program order)
    BGLL(0, 0);
    MEMPIN;
    ALOAD(0, 0);
    MEMPIN;
    ALOAD(1, 1);
    VMCNT(2);          // B0 + A0 done; A1 (2 loads) in flight
    AWRITE(0, 0);
    LGKM0;
    __builtin_amdgcn_s_barrier();
    __builtin_amdgcn_sched_barrier(0);

    // ---- phase 1 K-loop: S = x @ W2
    #pragma unroll
    for (int s = 0; s < 16; ++s) {
        const int p = s & 1;
        if (s < 15) BGLL(s + 1, p ^ 1);
        MEMPIN;
        if (s < 14) ALOAD(s + 2, s & 1);
        bf16x8 af[4], bf[8];
        #pragma unroll
        for (int m = 0; m < 4; ++m) af[m] = LDA1(p, m);
        #pragma unroll
        for (int n = 0; n < 8; ++n) bf[n] = LDB1(p, n);
        __builtin_amdgcn_s_setprio(1);
        #pragma unroll
        for (int m = 0; m < 4; ++m)
            #pragma unroll
            for (int n = 0; n < 8; ++n)
                acc[m][n] = __builtin_amdgcn_mfma_f32_16x16x32_bf16(af[m], bf[n], acc[m][n], 0, 0, 0);
        __builtin_amdgcn_s_setprio(0);
        if (s < 14) {
            VMCNT(2);                        // drain B(s+1) + A(s+1); leave A(s+2)
            AWRITE(p ^ 1, (s + 1) & 1);
            LGKM0;
            __builtin_amdgcn_s_barrier();
            __builtin_amdgcn_sched_barrier(0);
        } else if (s < 15) {
            VMCNT(0);
            AWRITE(p ^ 1, 1);
            LGKM0;
            __builtin_amdgcn_s_barrier();
            __builtin_amdgcn_sched_barrier(0);
        }
    }
    __syncthreads();   // all B reads done -> B region reusable for attn images
    #undef ALOAD
    #undef AWRITE
    #undef BGLL
    #undef LDA1
    #undef LDB1

    // ---- hoist phase-3 B(0) fragment loads (hide L2 latency under softmax)
    const char* b3 = W3fr + wn * 131072 + lane * 16;
    #define LB3(kt, buf)                                                           \
        { _Pragma("unroll")                                                        \
          for (int n = 0; n < 8; ++n)                                              \
              bb3[buf][n] = *(const bf16x8*)(b3 + ((n) >> 2) * 65536               \
                  + (size_t)(kt) * 4096 + ((n) & 3) * 1024); }
    bf16x8 bb3[2][8];
    LB3(0, 0);

    // ---- phase 2: softmax (wave-local heads) -> attn step-images in B region
    // pi-packed writes: thread's two values per image are slots 2lc, 2lc+1 ->
    // one u32 at row rl, granule lc>>2 (swizzled), byte (lc&3)*4.
    float b2v[8];
    #pragma unroll
    for (int n = 0; n < 8; ++n) b2v[n] = b2[wn * 128 + n * 16 + lc];

    #pragma unroll
    for (int m = 0; m < 4; ++m) {
        const int4 mv = *(const int4*)(mask + gr0 + m * 16 + grp * 4);
        const int mk[4] = {mv.x, mv.y, mv.z, mv.w};
        #pragma unroll
        for (int hl = 0; hl < 2; ++hl) {
            #pragma unroll
            for (int j = 0; j < 4; ++j) {
                float s0 = (acc[m][hl * 4 + 0][j] + b2v[hl * 4 + 0]) * 0.125f;
                float s1 = (acc[m][hl * 4 + 1][j] + b2v[hl * 4 + 1]) * 0.125f;
                float s2 = (acc[m][hl * 4 + 2][j] + b2v[hl * 4 + 2]) * 0.125f;
                float s3 = (acc[m][hl * 4 + 3][j] + b2v[hl * 4 + 3]) * 0.125f;
                float mx = fmaxf(fmaxf(s0, s1), fmaxf(s2, s3));
                mx = fmaxf(mx, __shfl_xor(mx, 1));
                mx = fmaxf(mx, __shfl_xor(mx, 2));
                mx = fmaxf(mx, __shfl_xor(mx, 4));
                mx = fmaxf(mx, __shfl_xor(mx, 8));
                float p0 = __expf(s0 - mx);
                float p1 = __expf(s1 - mx);
                float p2 = __expf(s2 - mx);
                float p3 = __expf(s3 - mx);
                float sm = (p0 + p1) + (p2 + p3);
                sm += __shfl_xor(sm, 1);
                sm += __shfl_xor(sm, 2);
                sm += __shfl_xor(sm, 4);
                sm += __shfl_xor(sm, 8);
                float a0, a1, a2, a3;
                if (mk[j] == 0) {
                    a0 = a1 = a2 = a3 = 0.015625f;   // fp32 -1e9 bias -> uniform attn
                } else {
                    const float inv = 1.0f / sm;
                    a0 = p0 * inv; a1 = p1 * inv; a2 = p2 * inv; a3 = p3 * inv;
                }
                const int rl = m * 16 + grp * 4 + j;
                const int gp = ((lc >> 2) ^ (rl & 3) ^ ((rl >> 2) & 3)) & 3;
                const int base = 8192 + rl * 64 + (gp << 4) + (lc & 3) * 4;
                const int si0 = wn * 4 + hl * 2;
                *(unsigned*)(ldsb + base + si0 * 4096)       = pk2(a0, a1);
                *(unsigned*)(ldsb + base + (si0 + 1) * 4096) = pk2(a2, a3);
            }
        }
    }
    __syncthreads();   // attn images complete

    // ---- phase 3: out = attn @ W3 (A from LDS images, B reg-streamed), no barriers
    #define LDA3(s, m)                                                             \
        (*(const bf16x8*)(ldsb + 8192 + (s) * 4096 + ((m) * 16 + lc) * 64          \
            + (((grp ^ (lc & 3) ^ (((m) * 4 + (lc >> 2)) & 3)) & 3) << 4)))

    #pragma unroll
    for (int m = 0; m < 4; ++m)
        #pragma unroll
        for (int n = 0; n < 8; ++n) acc[m][n] = (f32x4){0.f, 0.f, 0.f, 0.f};

    #pragma unroll
    for (int s = 0; s < 16; ++s) {
        const int p = s & 1;
        if (s < 15) LB3(s + 1, p ^ 1);
        bf16x8 af[4];
        #pragma unroll
        for (int m = 0; m < 4; ++m) af[m] = LDA3(s, m);
        __builtin_amdgcn_s_setprio(1);
        #pragma unroll
        for (int m = 0; m < 4; ++m)
            #pragma unroll
            for (int n = 0; n < 8; ++n)
                acc[m][n] = __builtin_amdgcn_mfma_f32_16x16x32_bf16(af[m], bb3[p][n], acc[m][n], 0, 0, 0);
        __builtin_amdgcn_s_setprio(0);
    }
    #undef LB3
    #undef LDA3

    // ---- epilogue: + bo, non-temporal row-major stores
    float bov[8];
    #pragma unroll
    for (int n = 0; n < 8; ++n) bov[n] = bo[wn * 128 + n * 16 + lc];

    #pragma unroll
    for (int m = 0; m < 4; ++m) {
        #pragma unroll
        for (int j = 0; j < 4; ++j) {
            const int gr = gr0 + m * 16 + grp * 4 + j;
            float* orow = out + (size_t)gr * DD + wn * 128 + lc;
            #pragma unroll
            for (int n = 0; n < 8; ++n)
                __builtin_nontemporal_store(acc[m][n][j] + bov[n], orow + n * 16);
        }
    }
}

extern "C" void kernel_launch(void* const* d_in, const int* in_sizes, int n_in,
                              void* d_out, int out_size, void* d_ws, size_t ws_size,
                              hipStream_t stream) {
    const float* qf     = (const float*)d_in[0];
    const int*   mask   = (const int*)d_in[1];
    const float* memory = (const float*)d_in[2];
    const float* Wq     = (const float*)d_in[3];
    const float* bq     = (const float*)d_in[4];
    const float* Wk     = (const float*)d_in[5];
    const float* bk     = (const float*)d_in[6];
    const float* Wv     = (const float*)d_in[7];
    const float* bv     = (const float*)d_in[8];
    const float* Wo     = (const float*)d_in[9];
    const float* bo     = (const float*)d_in[10];

    char* ws = (char*)d_ws;
    float* kproj = (float*)ws;                   // 128 KB
    float* vproj = (float*)(ws + 131072);        // 128 KB
    float* b2    = (float*)(ws + 262144);        // 2 KB
    char*  W2img = ws + 264192;                  // 512 KB (16 step-images)
    char*  W3fr  = ws + 788480;                  // 512 KB (fragment-linear, pi-k)

    prep_kv<<<32, 256, 0, stream>>>(memory, Wk, bk, Wv, bv, kproj, vproj);
    prep_w<<<64, 256, 0, stream>>>(Wq, bq, Wo, kproj, vproj, W2img, b2, W3fr);
    attn_fused<<<NROWS / 64, 256, 0, stream>>>(qf, mask, W2img, b2, W3fr, bo, (float*)d_out);
}

// Round 19
// 261.545 us; speedup vs baseline: 1.2188x; 1.0646x over previous
//
#include <hip/hip_runtime.h>
#include <hip/hip_bf16.h>

#define DD 512
#define HDIM 64
#define NROWS 131072

typedef __bf16 bf16x8 __attribute__((ext_vector_type(8)));
typedef float f32x4 __attribute__((ext_vector_type(4)));
typedef __bf16 bf16x2 __attribute__((ext_vector_type(2)));

static __device__ __forceinline__ unsigned bfbits(float f) {
    union { float f; unsigned u; } x; x.f = f;
    unsigned r = x.u + 0x7fffu + ((x.u >> 16) & 1u);
    return r >> 16;
}
static __device__ __forceinline__ __bf16 to_bf16(float f) {
    union { unsigned short s; __bf16 b; } y; y.s = (unsigned short)bfbits(f); return y.b;
}
// packed f32->bf16 pair via native casts (compiler fuses to v_cvt_pk_bf16_f32)
static __device__ __forceinline__ unsigned pk2(float lo, float hi) {
    bf16x2 t; t[0] = (__bf16)lo; t[1] = (__bf16)hi;
    union { bf16x2 b; unsigned u; } z; z.b = t; return z.u;
}

// Step-image element offset: p = row index, g = k-granule (8 bf16), e = elem.
// Double-XOR granule swizzle -> ds_read_b128 frag reads ~2-way.
static __device__ __forceinline__ int imgoff(int p, int g, int e) {
    return p * 64 + ((((g) ^ ((p) & 3) ^ (((p) >> 2) & 3)) & 3) << 4) + e * 2;
}

// Fragment-linear byte offset for a [512 cols][512 k] bf16 weight matrix:
// addr = ((c>>6)*64 + (d>>5)*4 + ((c>>4)&3))*1024 + slot*16 + (d&7)*2,
// slot = ((d>>3)&3)*16 + (c&15).  A wave frag load = base + lane*16 (coalesced).
static __device__ __forceinline__ size_t fragoff(int c, int d) {
    return (size_t)((((c >> 6) * 64 + (d >> 5) * 4 + ((c >> 4) & 3)) << 10)
         + (((((d >> 3) & 3) << 4) + (c & 15)) << 4) + ((d & 7) << 1));
}

// bijective XCD-chunk swizzle (m204); 2048 % 8 == 0 -> simple form is exact
static __device__ __forceinline__ int xcd_swz(int bid, int nwg) {
    const int q = nwg >> 3, r = nwg & 7;
    const int xcd = bid & 7, idx = bid >> 3;
    return (xcd < r ? xcd * (q + 1) : r * (q + 1) + (xcd - r) * q) + idx;
}

// ---------------- prep 1: k/v projections (tiled, W read once) ----------------
__global__ __launch_bounds__(256) void prep_kv(
    const float* __restrict__ memory,
    const float* __restrict__ Wk, const float* __restrict__ bk,
    const float* __restrict__ Wv, const float* __restrict__ bv,
    float* __restrict__ kproj, float* __restrict__ vproj) {
    __shared__ float memLds[64 * 65];
    __shared__ float wLds[32 * 65];
    const int t = threadIdx.x;
    const int b = blockIdx.x;
    const int mat = b >> 4;
    const int j0 = (b & 15) * 32;
    const float* W = mat ? Wv : Wk;
    const float* bias = mat ? bv : bk;
    float* proj = mat ? vproj : kproj;

    const int jloc = t >> 3;     // 0..31
    const int mbase = t & 7;
    float acc[8] = {0.f, 0.f, 0.f, 0.f, 0.f, 0.f, 0.f, 0.f};

    for (int dt = 0; dt < 8; ++dt) {
        const int d0 = dt * 64;
        __syncthreads();
        #pragma unroll
        for (int r = 0; r < 16; ++r) {
            const int row = r * 4 + (t >> 6);
            const int dd = t & 63;
            memLds[row * 65 + dd] = memory[(size_t)row * DD + d0 + dd];
        }
        #pragma unroll
        for (int r = 0; r < 8; ++r) {
            const int row = r * 4 + (t >> 6);
            const int dd = t & 63;
            wLds[row * 65 + dd] = W[(size_t)(j0 + row) * DD + d0 + dd];
        }
        __syncthreads();
        for (int d = 0; d < 64; ++d) {
            const float wv = wLds[jloc * 65 + d];
            #pragma unroll
            for (int i = 0; i < 8; ++i)
                acc[i] += memLds[(mbase + i * 8) * 65 + d] * wv;
        }
    }
    const float bj = bias[j0 + jloc];
    #pragma unroll
    for (int i = 0; i < 8; ++i)
        proj[(size_t)(mbase + i * 8) * DD + j0 + jloc] = acc[i] + bj;
}

// ---------------- prep 2: fold into W2fr / b2 / W3fr (fragment-linear) --------
// W2fr: fragment-linear [score-col c][k-dim d] (same layout family as W3fr).
// W3fr: fragment-linear [out-col j][k-dim c], k pi-permuted within 32-blocks.
__global__ __launch_bounds__(256) void prep_w(
    const float* __restrict__ Wq, const float* __restrict__ bq,
    const float* __restrict__ Wo,
    const float* __restrict__ kproj, const float* __restrict__ vproj,
    char* __restrict__ W2fr, float* __restrict__ b2,
    char* __restrict__ W3fr) {
    __shared__ float aLds[64 * 65];
    __shared__ float bLds[64 * 65];
    const int t = threadIdx.x;
    const int b = blockIdx.x;

    if (b < 32) {
        const int h = b >> 2, dq = b & 3;
        #pragma unroll
        for (int r = 0; r < 16; ++r) {
            const int row = r * 4 + (t >> 6), col = t & 63;
            aLds[row * 65 + col] = kproj[(size_t)row * DD + h * 64 + col];   // kp[m][hd]
        }
        __syncthreads();
        if (dq == 0 && t < 64) {
            float s = 0.f;
            for (int hd = 0; hd < 64; ++hd) s += bq[h * 64 + hd] * aLds[t * 65 + hd];
            b2[h * 64 + t] = s;
        }
        for (int dt = 0; dt < 2; ++dt) {
            const int d0 = dq * 128 + dt * 64;
            __syncthreads();
            #pragma unroll
            for (int r = 0; r < 16; ++r) {
                const int row = r * 4 + (t >> 6), col = t & 63;
                bLds[row * 65 + col] = Wq[(size_t)(h * 64 + row) * DD + d0 + col]; // wq[hd][d]
            }
            __syncthreads();
            #pragma unroll
            for (int uu = 0; uu < 2; ++uu) {
                const int u = t + 256 * uu;
                const int m = u & 63, oct = u >> 6;   // oct 0..7
                float acc[8] = {0.f, 0.f, 0.f, 0.f, 0.f, 0.f, 0.f, 0.f};
                for (int hd = 0; hd < 64; ++hd) {
                    const float kv = aLds[m * 65 + hd];
                    #pragma unroll
                    for (int e = 0; e < 8; ++e)
                        acc[e] += kv * bLds[hd * 65 + oct * 8 + e];
                }
                const int d = d0 + oct * 8;
                bf16x8 v;
                #pragma unroll
                for (int e = 0; e < 8; ++e) v[e] = to_bf16(acc[e]);
                *(bf16x8*)(W2fr + fragoff(h * 64 + m, d)) = v;   // frag-linear now
            }
        }
    } else {
        const int hc = (b - 32) >> 2, jq = (b - 32) & 3;
        #pragma unroll
        for (int r = 0; r < 16; ++r) {
            const int row = r * 4 + (t >> 6), col = t & 63;
            aLds[row * 65 + col] = vproj[(size_t)row * DD + hc * 64 + col];  // vp[mc][hd]
        }
        for (int jt = 0; jt < 2; ++jt) {
            const int j0 = jq * 128 + jt * 64;
            __syncthreads();
            #pragma unroll
            for (int r = 0; r < 16; ++r) {
                const int row = r * 4 + (t >> 6), col = t & 63;
                bLds[row * 65 + col] = Wo[(size_t)(j0 + row) * DD + hc * 64 + col]; // wo[jl][hd]
            }
            __syncthreads();
            #pragma unroll
            for (int uu = 0; uu < 2; ++uu) {
                const int u = t + 256 * uu;
                const int jl = u & 63, w = u >> 6;       // w 0..7
                const int blk = w >> 2, oct = w & 3;
                float acc[8] = {0.f, 0.f, 0.f, 0.f, 0.f, 0.f, 0.f, 0.f};
                for (int hd = 0; hd < 64; ++hd) {
                    const float wv = bLds[jl * 65 + hd];
                    #pragma unroll
                    for (int e = 0; e < 8; ++e) {
                        const int s = oct * 8 + e;
                        const int cl = (s >> 1) + ((s & 1) << 4);   // inverse pi
                        acc[e] += wv * aLds[(blk * 32 + cl) * 65 + hd];
                    }
                }
                const int cp0 = hc * 64 + blk * 32 + oct * 8;       // permuted k index
                bf16x8 v;
                #pragma unroll
                for (int e = 0; e < 8; ++e) v[e] = to_bf16(acc[e]);
                *(bf16x8*)(W3fr + fragoff(j0 + jl, cp0)) = v;
            }
        }
    }
}

// ---------------- fused kernel: x@W2 + b2 -> softmax -> @W3 + bo -> out -------
// Block: 64 rows x 512 cols, 4 waves; wave wn = cols [wn*128, +128) = heads
// 2wn, 2wn+1. acc[4][8] = 128 AGPR. LDS 64KB: 16 x step-images (4KB each),
// pre-staged ONCE; after phase 1 the same region holds the 16 attn images.
// W2 AND W3 stream frag-linear L2 -> registers (reg-dbuf). Only 3 barriers:
// post-stage, post-phase1, post-softmax. Waves otherwise free-run.
__global__ __launch_bounds__(256, 2) void attn_fused(
    const float* __restrict__ x, const int* __restrict__ mask,
    const char* __restrict__ W2fr, const float* __restrict__ b2,
    const char* __restrict__ W3fr, const float* __restrict__ bo,
    float* __restrict__ out) {
    __shared__ char ldsb[65536];

    const int tid = threadIdx.x;
    const int lane = tid & 63;
    const int wn = tid >> 6;              // 0..3: col quarter (2 heads)
    const int lc = lane & 15, grp = lane >> 4;
    const int swz = xcd_swz(blockIdx.x, gridDim.x);
    const int gr0 = swz * 64;

    // ---- stage ALL 16 x step-images (fp32 NT load -> bf16 image), once
    {
        const int gg = tid & 63;          // granule within row
        const int si = gg >> 2, g = gg & 3;
        #pragma unroll
        for (int it = 0; it < 16; ++it) {
            const int r = it * 4 + (tid >> 6);
            const float* px = x + (size_t)(gr0 + r) * DD + gg * 8;
            const f32x4 lo = __builtin_nontemporal_load((const f32x4*)px);
            const f32x4 hi = __builtin_nontemporal_load((const f32x4*)(px + 4));
            uint4 u;
            u.x = pk2(lo[0], lo[1]); u.y = pk2(lo[2], lo[3]);
            u.z = pk2(hi[0], hi[1]); u.w = pk2(hi[2], hi[3]);
            *(uint4*)(ldsb + si * 4096 + imgoff(r, g, 0)) = u;
        }
    }
    __syncthreads();

    // frag-linear weight loaders (both phases identical pattern, coalesced 1KB)
    const char* b1 = W2fr + wn * 131072 + lane * 16;
    const char* b3 = W3fr + wn * 131072 + lane * 16;
    #define LB1(kt, buf)                                                           \
        { _Pragma("unroll")                                                        \
          for (int n = 0; n < 8; ++n)                                              \
              bb1[buf][n] = *(const bf16x8*)(b1 + ((n) >> 2) * 65536               \
                  + (size_t)(kt) * 4096 + ((n) & 3) * 1024); }
    #define LB3(kt, buf)                                                           \
        { _Pragma("unroll")                                                        \
          for (int n = 0; n < 8; ++n)                                              \
              bb3[buf][n] = *(const bf16x8*)(b3 + ((n) >> 2) * 65536               \
                  + (size_t)(kt) * 4096 + ((n) & 3) * 1024); }
    // x / attn image fragment read (swizzle XOR compile-time per m)
    #define LDIMG(s, m)                                                            \
        (*(const bf16x8*)(ldsb + (s) * 4096 + ((m) * 16 + lc) * 64                 \
            + (((grp ^ (lc & 3) ^ (((m) * 4 + (lc >> 2)) & 3)) & 3) << 4)))

    f32x4 acc[4][8];
    #pragma unroll
    for (int m = 0; m < 4; ++m)
        #pragma unroll
        for (int n = 0; n < 8; ++n) acc[m][n] = (f32x4){0.f, 0.f, 0.f, 0.f};

    // ---- phase 1: S = x @ W2, barrier-free per-wave loop, W2 reg-dbuf
    bf16x8 bb1[2][8];
    LB1(0, 0);
    #pragma unroll
    for (int s = 0; s < 16; ++s) {
        const int p = s & 1;
        if (s < 15) LB1(s + 1, p ^ 1);
        bf16x8 af[4];
        #pragma unroll
        for (int m = 0; m < 4; ++m) af[m] = LDIMG(s, m);
        __builtin_amdgcn_s_setprio(1);
        #pragma unroll
        for (int m = 0; m < 4; ++m)
            #pragma unroll
            for (int n = 0; n < 8; ++n)
                acc[m][n] = __builtin_amdgcn_mfma_f32_16x16x32_bf16(af[m], bb1[p][n], acc[m][n], 0, 0, 0);
        __builtin_amdgcn_s_setprio(0);
    }
    #undef LB1
    __syncthreads();   // all waves done reading x-images -> region reusable

    // ---- hoist phase-3 B(0) fragment loads (hide L2 latency under softmax)
    bf16x8 bb3[2][8];
    LB3(0, 0);

    // ---- phase 2: softmax (wave-local heads) -> attn step-images (pi-packed)
    float b2v[8];
    #pragma unroll
    for (int n = 0; n < 8; ++n) b2v[n] = b2[wn * 128 + n * 16 + lc];

    #pragma unroll
    for (int m = 0; m < 4; ++m) {
        const int4 mv = *(const int4*)(mask + gr0 + m * 16 + grp * 4);
        const int mk[4] = {mv.x, mv.y, mv.z, mv.w};
        #pragma unroll
        for (int hl = 0; hl < 2; ++hl) {
            #pragma unroll
            for (int j = 0; j < 4; ++j) {
                float s0 = (acc[m][hl * 4 + 0][j] + b2v[hl * 4 + 0]) * 0.125f;
                float s1 = (acc[m][hl * 4 + 1][j] + b2v[hl * 4 + 1]) * 0.125f;
                float s2 = (acc[m][hl * 4 + 2][j] + b2v[hl * 4 + 2]) * 0.125f;
                float s3 = (acc[m][hl * 4 + 3][j] + b2v[hl * 4 + 3]) * 0.125f;
                float mx = fmaxf(fmaxf(s0, s1), fmaxf(s2, s3));
                mx = fmaxf(mx, __shfl_xor(mx, 1));
                mx = fmaxf(mx, __shfl_xor(mx, 2));
                mx = fmaxf(mx, __shfl_xor(mx, 4));
                mx = fmaxf(mx, __shfl_xor(mx, 8));
                float p0 = __expf(s0 - mx);
                float p1 = __expf(s1 - mx);
                float p2 = __expf(s2 - mx);
                float p3 = __expf(s3 - mx);
                float sm = (p0 + p1) + (p2 + p3);
                sm += __shfl_xor(sm, 1);
                sm += __shfl_xor(sm, 2);
                sm += __shfl_xor(sm, 4);
                sm += __shfl_xor(sm, 8);
                float a0, a1, a2, a3;
                if (mk[j] == 0) {
                    a0 = a1 = a2 = a3 = 0.015625f;   // fp32 -1e9 bias -> uniform attn
                } else {
                    const float inv = 1.0f / sm;
                    a0 = p0 * inv; a1 = p1 * inv; a2 = p2 * inv; a3 = p3 * inv;
                }
                const int rl = m * 16 + grp * 4 + j;
                const int gp = ((lc >> 2) ^ (rl & 3) ^ ((rl >> 2) & 3)) & 3;
                const int base = rl * 64 + (gp << 4) + (lc & 3) * 4;
                const int si0 = wn * 4 + hl * 2;
                *(unsigned*)(ldsb + base + si0 * 4096)       = pk2(a0, a1);
                *(unsigned*)(ldsb + base + (si0 + 1) * 4096) = pk2(a2, a3);
            }
        }
    }
    __syncthreads();   // attn images complete

    // ---- phase 3: out = attn @ W3 (A from LDS images, B reg-dbuf), no barriers
    #pragma unroll
    for (int m = 0; m < 4; ++m)
        #pragma unroll
        for (int n = 0; n < 8; ++n) acc[m][n] = (f32x4){0.f, 0.f, 0.f, 0.f};

    #pragma unroll
    for (int s = 0; s < 16; ++s) {
        const int p = s & 1;
        if (s < 15) LB3(s + 1, p ^ 1);
        bf16x8 af[4];
        #pragma unroll
        for (int m = 0; m < 4; ++m) af[m] = LDIMG(s, m);
        __builtin_amdgcn_s_setprio(1);
        #pragma unroll
        for (int m = 0; m < 4; ++m)
            #pragma unroll
            for (int n = 0; n < 8; ++n)
                acc[m][n] = __builtin_amdgcn_mfma_f32_16x16x32_bf16(af[m], bb3[p][n], acc[m][n], 0, 0, 0);
        __builtin_amdgcn_s_setprio(0);
    }
    #undef LB3
    #undef LDIMG

    // ---- epilogue: + bo, non-temporal row-major stores
    float bov[8];
    #pragma unroll
    for (int n = 0; n < 8; ++n) bov[n] = bo[wn * 128 + n * 16 + lc];

    #pragma unroll
    for (int m = 0; m < 4; ++m) {
        #pragma unroll
        for (int j = 0; j < 4; ++j) {
            const int gr = gr0 + m * 16 + grp * 4 + j;
            float* orow = out + (size_t)gr * DD + wn * 128 + lc;
            #pragma unroll
            for (int n = 0; n < 8; ++n)
                __builtin_nontemporal_store(acc[m][n][j] + bov[n], orow + n * 16);
        }
    }
}

extern "C" void kernel_launch(void* const* d_in, const int* in_sizes, int n_in,
                              void* d_out, int out_size, void* d_ws, size_t ws_size,
                              hipStream_t stream) {
    const float* qf     = (const float*)d_in[0];
    const int*   mask   = (const int*)d_in[1];
    const float* memory = (const float*)d_in[2];
    const float* Wq     = (const float*)d_in[3];
    const float* bq     = (const float*)d_in[4];
    const float* Wk     = (const float*)d_in[5];
    const float* bk     = (const float*)d_in[6];
    const float* Wv     = (const float*)d_in[7];
    const float* bv     = (const float*)d_in[8];
    const float* Wo     = (const float*)d_in[9];
    const float* bo     = (const float*)d_in[10];

    char* ws = (char*)d_ws;
    float* kproj = (float*)ws;                   // 128 KB
    float* vproj = (float*)(ws + 131072);        // 128 KB
    float* b2    = (float*)(ws + 262144);        // 2 KB
    char*  W2fr  = ws + 264192;                  // 512 KB (fragment-linear)
    char*  W3fr  = ws + 788480;                  // 512 KB (fragment-linear, pi-k)

    prep_kv<<<32, 256, 0, stream>>>(memory, Wk, bk, Wv, bv, kproj, vproj);
    prep_w<<<64, 256, 0, stream>>>(Wq, bq, Wo, kproj, vproj, W2fr, b2, W3fr);
    attn_fused<<<NROWS / 64, 256, 0, stream>>>(qf, mask, W2fr, b2, W3fr, bo, (float*)d_out);
}